// Round 9
// baseline (135.097 us; speedup 1.0000x reference)
//
#include <hip/hip_runtime.h>

// Maj3: out[b,o,h,w] = sum_{kh,c} sign( sum_{kw} x[b,c,h+kh-1,w+kw-1] * W[o,kw,kh,c] )
// x: (4,64,56,56) f32; W: (64,3,3,64) f32; out: (4,64,56,56) f32.
// Bit-exactness vs numpy required (integer output, threshold 1.36): no FMA
// contraction (contract(off) pragma — verified holding, absmax stable 1.0),
// same per-channel mul/add order, sign(0)=0 only from fully-pad rows (skipped).
//
// R9: R8 showed VALU busy-time (~20us) is near the 7-op/sign floor (~17us) but
// stall time ~20us — exposed VMEM latency (x-load issued inside the compute
// loop) + SGPR-choked s_load lookahead. Fix: per kh-row, PRELOAD all 16 row
// values into a VGPR array (16 VMEM in flight, fully unrolled, static idx),
// then a pure-register compute sweep (DPP neighbors + 8-oo sign bodies) with
// no VMEM dependence. Weight s_loads hide under 448-instr unroll groups.

#define Cn 64
#define Hn 56
#define Wn 56
#define On 64
#define OG 8    // output channels per block (uniform -> scalar weight loads)
#define CH 16   // channels per wave (c-quarter)

#define DPP_WAVE_SHL1 0x130
#define DPP_WAVE_SHR1 0x138

// Whole-wave shift by one lane; out-of-range source lanes read 0 (exact pad).
__device__ __forceinline__ float dpp_shift(float s, const int ctrl_is_shr) {
    const int si = __builtin_bit_cast(int, s);
    const int r  = ctrl_is_shr
        ? __builtin_amdgcn_update_dpp(0, si, DPP_WAVE_SHR1, 0xf, 0xf, true)
        : __builtin_amdgcn_update_dpp(0, si, DPP_WAVE_SHL1, 0xf, 0xf, true);
    return __builtin_bit_cast(float, r);
}

__global__ __launch_bounds__(256, 7)
void maj3_kernel(const float* __restrict__ x,
                 const float* __restrict__ wt,
                 float* __restrict__ out)
{
#pragma clang fp contract(off)
    __shared__ int lds[3][OG][64];   // slabs for c-quarters 1..3

    const int lane   = threadIdx.x & 63;
    // Wave-uniform; readfirstlane keeps rows/weight addresses on the scalar path.
    const int cq     = __builtin_amdgcn_readfirstlane((int)(threadIdx.x >> 6)); // 0..3
    const int bh     = blockIdx.x;        // 0..223: one (b,h) row per block
    const int b      = bh / Hn;
    const int h      = bh - b * Hn;
    const int og     = blockIdx.y * OG;   // block-uniform o base

    const int wc     = lane;              // pixel column; lanes >=56 inactive
    const bool act   = wc < Wn;
    const int c1     = min(wc, Wn - 1);   // clamped own-tap address

    int acc[OG];
    #pragma unroll
    for (int i = 0; i < OG; ++i) acc[i] = 0;

    int nvalid = 0;
    const float* xb = x + b * (Cn * Hn * Wn) + cq * (CH * Hn * Wn);

    for (int kh = 0; kh < 3; ++kh) {
        const int row = h + kh - 1;
        if (row < 0 || row >= Hn) continue;   // fully-pad row: sign(0)=0, skip
        ++nvalid;
        const float* xr = xb + row * Wn;

        // Phase 1: preload the whole row slice -> 16 independent VMEM loads in
        // flight; lane-zeroing folded in. Fully unrolled -> stays in VGPRs.
        float x1v[CH];
        #pragma unroll
        for (int c = 0; c < CH; ++c) {
            const float v = xr[c * (Hn * Wn) + c1];
            x1v[c] = act ? v : 0.0f;          // zero lanes >=56
        }

        // Phase 2: pure-register compute sweep (no VMEM dependence).
        #pragma unroll 8
        for (int c = 0; c < CH; ++c) {
            const float x1 = x1v[c];
            const float x0 = dpp_shift(x1, 1);    // x[wc-1]; lane0 -> +0 pad
            const float x2 = dpp_shift(x1, 0);    // x[wc+1]; lane55 -> +0 pad
            #pragma unroll
            for (int oo = 0; oo < OG; ++oo) {
                // W[o,kw,kh,c] = wt[o*576 + kw*192 + kh*64 + c]; fully uniform
                // address -> s_load clusters on the scalar path.
                const float* wp = wt + (og + oo) * (3 * 3 * Cn) + kh * Cn
                                + cq * CH + c;
                const float p0 = x0 * wp[0 * 3 * Cn];   // contract(off):
                const float p1 = x1 * wp[1 * 3 * Cn];   //   plain v_mul_f32,
                const float p2 = x2 * wp[2 * 3 * Cn];   //   no v_fmac fusion
                const float s  = (p0 + p1) + p2;        // same order as reference
                acc[oo] += (int)(__float_as_uint(s) >> 31);  // count negatives
            }
        }
    }

    // Combine the four c-quarters' negative-counts (integer -> exact).
    if (cq != 0) {
        #pragma unroll
        for (int oo = 0; oo < OG; ++oo) lds[cq - 1][oo][lane] = acc[oo];
    }
    __syncthreads();
    if (cq == 0 && act) {
        float* ob = out + ((b * On + og) * Hn + h) * Wn + wc;
        const float base = (float)(nvalid * Cn);
        #pragma unroll
        for (int oo = 0; oo < OG; ++oo) {
            const int total = acc[oo] + lds[0][oo][lane]
                            + lds[1][oo][lane] + lds[2][oo][lane];
            ob[oo * Hn * Wn] = base - 2.0f * (float)total;  // N - 2*negcount
        }
    }
}

extern "C" void kernel_launch(void* const* d_in, const int* in_sizes, int n_in,
                              void* d_out, int out_size, void* d_ws, size_t ws_size,
                              hipStream_t stream) {
    const float* x  = (const float*)d_in[0];
    const float* wt = (const float*)d_in[1];
    float* o        = (float*)d_out;
    dim3 grid(224, 8);   // 224 (b,h) rows x 8 o-groups of 8
    maj3_kernel<<<grid, dim3(256), 0, stream>>>(x, wt, o);
}

// Round 10
// 125.657 us; speedup vs baseline: 1.0751x; 1.0751x over previous
//
#include <hip/hip_runtime.h>

// Maj3: out[b,o,h,w] = sum_{kh,c} sign( sum_{kw} x[b,c,h+kh-1,w+kw-1] * W[o,kw,kh,c] )
// x: (4,64,56,56) f32; W: (64,3,3,64) f32; out: (4,64,56,56) f32.
// Bit-exactness vs numpy required (integer output, threshold 1.36): no FMA
// contraction (contract(off) pragma — verified holding, absmax stable 1.0),
// same per-channel mul/add order, sign(0)=0 only from fully-pad rows (skipped).
//
// R10: R9's preload was right, its `#pragma unroll 8` was the bug — partial
// unroll leaves x1v[] runtime-indexed (rule #20) -> select/waterfall lowering,
// 5x VALU (VALUBusy 80% @ 138us). Fix: FULL unroll of the compute sweep so
// x1v[] register-allocates (16 VGPRs). Phase 1: 16 VMEM loads in flight;
// phase 2: pure-register compute (DPP neighbors + 8-oo sign bodies).

#define Cn 64
#define Hn 56
#define Wn 56
#define On 64
#define OG 8    // output channels per block (uniform -> scalar weight loads)
#define CH 16   // channels per wave (c-quarter)

#define DPP_WAVE_SHL1 0x130
#define DPP_WAVE_SHR1 0x138

// Whole-wave shift by one lane; out-of-range source lanes read 0 (exact pad).
__device__ __forceinline__ float dpp_shift(float s, const int ctrl_is_shr) {
    const int si = __builtin_bit_cast(int, s);
    const int r  = ctrl_is_shr
        ? __builtin_amdgcn_update_dpp(0, si, DPP_WAVE_SHR1, 0xf, 0xf, true)
        : __builtin_amdgcn_update_dpp(0, si, DPP_WAVE_SHL1, 0xf, 0xf, true);
    return __builtin_bit_cast(float, r);
}

__global__ __launch_bounds__(256, 7)
void maj3_kernel(const float* __restrict__ x,
                 const float* __restrict__ wt,
                 float* __restrict__ out)
{
#pragma clang fp contract(off)
    __shared__ int lds[3][OG][64];   // slabs for c-quarters 1..3

    const int lane   = threadIdx.x & 63;
    // Wave-uniform; readfirstlane keeps rows/weight addresses on the scalar path.
    const int cq     = __builtin_amdgcn_readfirstlane((int)(threadIdx.x >> 6)); // 0..3
    const int bh     = blockIdx.x;        // 0..223: one (b,h) row per block
    const int b      = bh / Hn;
    const int h      = bh - b * Hn;
    const int og     = blockIdx.y * OG;   // block-uniform o base

    const int wc     = lane;              // pixel column; lanes >=56 inactive
    const bool act   = wc < Wn;
    const int c1     = min(wc, Wn - 1);   // clamped own-tap address

    int acc[OG];
    #pragma unroll
    for (int i = 0; i < OG; ++i) acc[i] = 0;

    int nvalid = 0;
    const float* xb = x + b * (Cn * Hn * Wn) + cq * (CH * Hn * Wn);

    for (int kh = 0; kh < 3; ++kh) {
        const int row = h + kh - 1;
        if (row < 0 || row >= Hn) continue;   // fully-pad row: sign(0)=0, skip
        ++nvalid;
        const float* xr = xb + row * Wn;

        // Phase 1: preload the whole row slice (fully unrolled -> 16 VGPRs,
        // 16 independent VMEM loads in flight); lane-zeroing folded in.
        float x1v[CH];
        #pragma unroll
        for (int c = 0; c < CH; ++c) {
            const float v = xr[c * (Hn * Wn) + c1];
            x1v[c] = act ? v : 0.0f;          // zero lanes >=56
        }

        // Phase 2: pure-register compute sweep. FULL unroll: every x1v index
        // is a compile-time constant (rule #20 — keeps the array in VGPRs).
        #pragma unroll
        for (int c = 0; c < CH; ++c) {
            const float x1 = x1v[c];
            const float x0 = dpp_shift(x1, 1);    // x[wc-1]; lane0 -> +0 pad
            const float x2 = dpp_shift(x1, 0);    // x[wc+1]; lane55 -> +0 pad
            #pragma unroll
            for (int oo = 0; oo < OG; ++oo) {
                // W[o,kw,kh,c] = wt[o*576 + kw*192 + kh*64 + c]; fully uniform
                // address -> s_load clusters on the scalar path.
                const float* wp = wt + (og + oo) * (3 * 3 * Cn) + kh * Cn
                                + cq * CH + c;
                const float p0 = x0 * wp[0 * 3 * Cn];   // contract(off):
                const float p1 = x1 * wp[1 * 3 * Cn];   //   plain v_mul_f32,
                const float p2 = x2 * wp[2 * 3 * Cn];   //   no v_fmac fusion
                const float s  = (p0 + p1) + p2;        // same order as reference
                acc[oo] += (int)(__float_as_uint(s) >> 31);  // count negatives
            }
        }
    }

    // Combine the four c-quarters' negative-counts (integer -> exact).
    if (cq != 0) {
        #pragma unroll
        for (int oo = 0; oo < OG; ++oo) lds[cq - 1][oo][lane] = acc[oo];
    }
    __syncthreads();
    if (cq == 0 && act) {
        float* ob = out + ((b * On + og) * Hn + h) * Wn + wc;
        const float base = (float)(nvalid * Cn);
        #pragma unroll
        for (int oo = 0; oo < OG; ++oo) {
            const int total = acc[oo] + lds[0][oo][lane]
                            + lds[1][oo][lane] + lds[2][oo][lane];
            ob[oo * Hn * Wn] = base - 2.0f * (float)total;  // N - 2*negcount
        }
    }
}

extern "C" void kernel_launch(void* const* d_in, const int* in_sizes, int n_in,
                              void* d_out, int out_size, void* d_ws, size_t ws_size,
                              hipStream_t stream) {
    const float* x  = (const float*)d_in[0];
    const float* wt = (const float*)d_in[1];
    float* o        = (float*)d_out;
    dim3 grid(224, 8);   // 224 (b,h) rows x 8 o-groups of 8
    maj3_kernel<<<grid, dim3(256), 0, stream>>>(x, wt, o);
}

// Round 11
// 35.850 us; speedup vs baseline: 3.7684x; 3.5051x over previous
//
#include <hip/hip_runtime.h>

// Maj3: out[b,o,h,w] = sum_{kh,c} sign( sum_{kw} x[b,c,h+kh-1,w+kw-1] * W[o,kw,kh,c] )
// x: (4,64,56,56) f32; W: (64,3,3,64) f32; out: (4,64,56,56) f32.
// Bit-exactness vs numpy required (integer output, threshold 1.36): no FMA
// contraction (contract(off) pragma — verified holding, absmax stable 1.0),
// same per-channel mul/add order, sign(0)=0 only from fully-pad rows (skipped).
//
// R11: R10's full-row unroll exploded SGPR liveness (384 weight dwords hoisted
// -> scalar spill to scratch, 340MB traffic). Keep R8's 4c x 8oo tile (96
// weight dwords max live) but software-pipeline the x-loads ONE TILE AHEAD
// using named scalars (no arrays, no full unroll): next tile's 4 VMEM loads
// issue before the current tile's ~224 VALU ops, hiding x latency. Outer tile
// loop is unroll(disable) to stop re-merging. launch_bounds(256,8) -> 8
// waves/SIMD (VGPR cap 64, we need ~48) to hide the per-tile SMEM drains.

#define Cn 64
#define Hn 56
#define Wn 56
#define On 64
#define OG 8    // output channels per block (uniform -> scalar weight loads)
#define CH 16   // channels per wave (c-quarter); power of 2 (wrap mask)

#define DPP_WAVE_SHL1 0x130
#define DPP_WAVE_SHR1 0x138

// Whole-wave shift by one lane; out-of-range source lanes read 0 (exact pad).
__device__ __forceinline__ float dpp_shift(float s, const int ctrl_is_shr) {
    const int si = __builtin_bit_cast(int, s);
    const int r  = ctrl_is_shr
        ? __builtin_amdgcn_update_dpp(0, si, DPP_WAVE_SHR1, 0xf, 0xf, true)
        : __builtin_amdgcn_update_dpp(0, si, DPP_WAVE_SHL1, 0xf, 0xf, true);
    return __builtin_bit_cast(float, r);
}

// One channel's sign bodies for all OG output channels. x1 already zeroed for
// inactive lanes; neighbors by DPP (exact +0.0 pads at row ends).
#define CBODY(xv, cidx)                                                       \
    do {                                                                      \
        const float x1_ = (xv);                                               \
        const float x0_ = dpp_shift(x1_, 1);  /* x[wc-1] */                   \
        const float x2_ = dpp_shift(x1_, 0);  /* x[wc+1] */                   \
        _Pragma("unroll")                                                     \
        for (int oo = 0; oo < OG; ++oo) {                                     \
            const float* wp_ = wt + (og + oo) * (3 * 3 * Cn) + kh * Cn        \
                             + cq * CH + (cidx);                              \
            const float p0_ = x0_ * wp_[0 * 3 * Cn];  /* contract(off) */     \
            const float p1_ = x1_ * wp_[1 * 3 * Cn];                          \
            const float p2_ = x2_ * wp_[2 * 3 * Cn];                          \
            const float s_  = (p0_ + p1_) + p2_;      /* reference order */   \
            acc[oo] += (int)(__float_as_uint(s_) >> 31);                      \
        }                                                                     \
    } while (0)

__global__ __launch_bounds__(256, 8)
void maj3_kernel(const float* __restrict__ x,
                 const float* __restrict__ wt,
                 float* __restrict__ out)
{
#pragma clang fp contract(off)
    __shared__ int lds[3][OG][64];   // slabs for c-quarters 1..3

    const int lane   = threadIdx.x & 63;
    // Wave-uniform; readfirstlane keeps rows/weight addresses on the scalar path.
    const int cq     = __builtin_amdgcn_readfirstlane((int)(threadIdx.x >> 6)); // 0..3
    const int bh     = blockIdx.x;        // 0..223: one (b,h) row per block
    const int b      = bh / Hn;
    const int h      = bh - b * Hn;
    const int og     = blockIdx.y * OG;   // block-uniform o base

    const int wc     = lane;              // pixel column; lanes >=56 inactive
    const bool act   = wc < Wn;
    const int c1     = min(wc, Wn - 1);   // clamped own-tap address

#define LDX(cc) (act ? xr[(cc) * (Hn * Wn) + c1] : 0.0f)

    int acc[OG];
    #pragma unroll
    for (int i = 0; i < OG; ++i) acc[i] = 0;

    int nvalid = 0;
    const float* xb = x + b * (Cn * Hn * Wn) + cq * (CH * Hn * Wn);

    for (int kh = 0; kh < 3; ++kh) {
        const int row = h + kh - 1;
        if (row < 0 || row >= Hn) continue;   // fully-pad row: sign(0)=0, skip
        ++nvalid;
        const float* xr = xb + row * Wn;

        // Prologue: tile 0's x values in named regs.
        float xa0 = LDX(0), xa1 = LDX(1), xa2 = LDX(2), xa3 = LDX(3);

        #pragma clang loop unroll(disable)
        for (int ct = 0; ct < CH; ct += 4) {
            // Prefetch next tile (wraps to 0 on last iter: harmless reload).
            const int cn = (ct + 4) & (CH - 1);
            const float nb0 = LDX(cn + 0);
            const float nb1 = LDX(cn + 1);
            const float nb2 = LDX(cn + 2);
            const float nb3 = LDX(cn + 3);
            // Compute current tile: 4c x 8oo sign bodies (~224 VALU) hides
            // the prefetch latency; weight s_loads cluster per (oo,kw) into
            // dwordx4 over the 4 contiguous c.
            CBODY(xa0, ct + 0);
            CBODY(xa1, ct + 1);
            CBODY(xa2, ct + 2);
            CBODY(xa3, ct + 3);
            xa0 = nb0; xa1 = nb1; xa2 = nb2; xa3 = nb3;
        }
    }

    // Combine the four c-quarters' negative-counts (integer -> exact).
    if (cq != 0) {
        #pragma unroll
        for (int oo = 0; oo < OG; ++oo) lds[cq - 1][oo][lane] = acc[oo];
    }
    __syncthreads();
    if (cq == 0 && act) {
        float* ob = out + ((b * On + og) * Hn + h) * Wn + wc;
        const float base = (float)(nvalid * Cn);
        #pragma unroll
        for (int oo = 0; oo < OG; ++oo) {
            const int total = acc[oo] + lds[0][oo][lane]
                            + lds[1][oo][lane] + lds[2][oo][lane];
            ob[oo * Hn * Wn] = base - 2.0f * (float)total;  // N - 2*negcount
        }
    }
}

extern "C" void kernel_launch(void* const* d_in, const int* in_sizes, int n_in,
                              void* d_out, int out_size, void* d_ws, size_t ws_size,
                              hipStream_t stream) {
    const float* x  = (const float*)d_in[0];
    const float* wt = (const float*)d_in[1];
    float* o        = (float*)d_out;
    dim3 grid(224, 8);   // 224 (b,h) rows x 8 o-groups of 8
    maj3_kernel<<<grid, dim3(256), 0, stream>>>(x, wt, o);
}